// Round 4
// baseline (445.182 us; speedup 1.0000x reference)
//
#include <hip/hip_runtime.h>
#include <math.h>

typedef short s16x8 __attribute__((ext_vector_type(8)));
typedef short s16x4 __attribute__((ext_vector_type(4)));
typedef float f32x4 __attribute__((ext_vector_type(4)));

// ws float-offsets
#define POOLED_OFF 0           // 2048*80 = 163840 floats
#define W1PK_OFF   163840      // 128 rows x {w1c0,w1c1,w1c2,b1} = 512 floats
#define B2PK_OFF   164352      // 112 floats (zero-padded)
#define B3PK_OFF   164464      // 80 floats
#define WSHORT_OFF 164560      // short region starts here (16B aligned)
// short-offsets inside short region
#define W2H_S 0                // 7n*4ks*64lane*8 = 14336
#define W2L_S 14336
#define W3H_S 28672            // 5n*4ks*64*8 = 10240
#define W3L_S 38912            // end 49152 shorts

// split fp32 into bf16 hi + bf16 lo (truncation; dropped lo*lo ~2^-16 rel)
__device__ __forceinline__ void bsplit(float x, short& hi, short& lo) {
    unsigned u  = __float_as_uint(x);
    unsigned uh = u & 0xFFFF0000u;
    hi = (short)(uh >> 16);
    float r = x - __uint_as_float(uh);
    lo = (short)(__float_as_uint(r) >> 16);
}

// Prep: zero pooled, pack w1/b1 rows, pad biases, build frag-ordered split
// weights. Frag (n,ks): lane=ln+16*l4 holds w[16n+ln][ks*32+l4*8+j], j=0..7.
__global__ void ds_prep(const float* __restrict__ pw1, const float* __restrict__ pb1,
                        const float* __restrict__ pw2, const float* __restrict__ pb2,
                        const float* __restrict__ pw3, const float* __restrict__ pb3,
                        float* __restrict__ wsF, short* __restrict__ wsS) {
    int t = blockIdx.x * 256 + threadIdx.x;
    if (t < 40960) { f32x4 z = 0.f; *(f32x4*)(wsF + POOLED_OFF + t * 4) = z; return; }
    t -= 40960;
    if (t < 128) {
        f32x4 v = 0.f;
        if (t < 120) { v.x = pw1[t*3]; v.y = pw1[t*3+1]; v.z = pw1[t*3+2]; v.w = pb1[t]; }
        *(f32x4*)(wsF + W1PK_OFF + t * 4) = v; return;
    }
    t -= 128;
    if (t < 112) { wsF[B2PK_OFF + t] = (t < 100) ? pb2[t] : 0.f; return; }
    t -= 112;
    if (t < 80)  { wsF[B3PK_OFF + t] = pb3[t]; return; }
    t -= 80;
    if (t < 14336) {
        int j = t & 7, lane = (t >> 3) & 63, c = t >> 9;
        int ks = c & 3, n = c >> 2;
        int ln = lane & 15, l4 = lane >> 4;
        int row = 16 * n + ln, col = ks * 32 + l4 * 8 + j;
        float v = (row < 100 && col < 120) ? pw2[row * 120 + col] : 0.f;
        short hi, lo; bsplit(v, hi, lo);
        wsS[W2H_S + t] = hi; wsS[W2L_S + t] = lo; return;
    }
    t -= 14336;
    if (t < 10240) {
        int j = t & 7, lane = (t >> 3) & 63, c = t >> 9;
        int ks = c & 3, n = c >> 2;
        int ln = lane & 15, l4 = lane >> 4;
        int row = 16 * n + ln, col = ks * 32 + l4 * 8 + j;
        float v = (col < 100) ? pw3[row * 100 + col] : 0.f;
        short hi, lo; bsplit(v, hi, lo);
        wsS[W3H_S + t] = hi; wsS[W3L_S + t] = lo; return;
    }
}

// Phi: 256 blocks x 512 thr; block processes 8 batches; wave w owns el-tile w.
// No barriers in the batch loop. L2/L3 interleaved per k-slice (ks3) so only
// 2 acc2 tiles are ever live -> no register spills (launch_bounds(512,1)).
__global__ __launch_bounds__(512, 1)
void ds_phi(const float* __restrict__ dyn, const float* __restrict__ wsF,
            const short* __restrict__ wsS, float* __restrict__ pooledG) {
    const int tid = threadIdx.x;
    const int w = tid >> 6, l = tid & 63, ln = l & 15, l4 = l >> 4;
    const int klo = l4 * 8;

    __shared__ short sw2h[14336], sw2l[14336], sw3h[10240], sw3l[10240];
    __shared__ float sw1[512], sb2[112], sb3[80];
    __shared__ short bnH[4096], bnL[4096];      // per-wave 512-short bounce

    for (int i = tid; i < 1792; i += 512) *(s16x8*)(sw2h + i*8) = *(const s16x8*)(wsS + W2H_S + i*8);
    for (int i = tid; i < 1792; i += 512) *(s16x8*)(sw2l + i*8) = *(const s16x8*)(wsS + W2L_S + i*8);
    for (int i = tid; i < 1280; i += 512) *(s16x8*)(sw3h + i*8) = *(const s16x8*)(wsS + W3H_S + i*8);
    for (int i = tid; i < 1280; i += 512) *(s16x8*)(sw3l + i*8) = *(const s16x8*)(wsS + W3L_S + i*8);
    if (tid < 128) *(f32x4*)(sw1 + tid*4) = *(const f32x4*)(wsF + W1PK_OFF + tid*4);
    if (tid < 112) sb2[tid] = wsF[B2PK_OFF + tid];
    if (tid < 80)  sb3[tid] = wsF[B3PK_OFF + tid];
    __syncthreads();

    const int b0 = blockIdx.x * 8;
    const int el = 16 * w + ln;
    const int bnBase = w << 9;

    for (int g = 0; g < 8; ++g) {
        const int b = b0 + g;
        const float* xp = dyn + (size_t)b * 384 + el * 3;
        const float x0 = xp[0], x1 = xp[1], x2 = xp[2];

        // h1 B-frags born in registers (k>=120 rows are zero in sw1)
        s16x8 bh1[4], bl1[4];
        #pragma unroll
        for (int ks = 0; ks < 4; ++ks) {
            #pragma unroll
            for (int j = 0; j < 8; ++j) {
                const int k = ks * 32 + klo + j;
                f32x4 c = *(const f32x4*)(sw1 + 4 * k);
                float v = fmaf(x0, c.x, fmaf(x1, c.y, fmaf(x2, c.z, c.w)));
                v = fmaxf(v, 0.f);
                short hi, lo; bsplit(v, hi, lo);
                bh1[ks][j] = hi; bl1[ks][j] = lo;
            }
        }

        f32x4 acc3[5];
        #pragma unroll
        for (int n = 0; n < 5; ++n) acc3[n] = 0.f;

        // per k-slice of h2: finish the 2 needed L2 o-tiles, bounce, feed L3
        #pragma unroll
        for (int ks3 = 0; ks3 < 4; ++ks3) {
            #pragma unroll
            for (int nn = 0; nn < 2; ++nn) {
                const int n2 = 2 * ks3 + nn;
                s16x4 hh = 0, hl = 0;
                if (n2 < 7) {
                    f32x4 a2h = 0.f, a2x = 0.f;   // hi-path / cross-path (2x ILP)
                    #pragma unroll
                    for (int ks = 0; ks < 4; ++ks) {
                        const int off = ((n2 * 4 + ks) * 64 + l) * 8;
                        s16x8 ah = *(const s16x8*)(sw2h + off);
                        s16x8 al = *(const s16x8*)(sw2l + off);
                        a2h = __builtin_amdgcn_mfma_f32_16x16x32_bf16(ah, bh1[ks], a2h, 0, 0, 0);
                        a2x = __builtin_amdgcn_mfma_f32_16x16x32_bf16(ah, bl1[ks], a2x, 0, 0, 0);
                        a2x = __builtin_amdgcn_mfma_f32_16x16x32_bf16(al, bh1[ks], a2x, 0, 0, 0);
                    }
                    const int o0 = 16 * n2 + 4 * l4;
                    f32x4 bb = *(const f32x4*)(sb2 + o0);
                    #pragma unroll
                    for (int r = 0; r < 4; ++r) {
                        float v = fmaxf(a2h[r] + a2x[r] + bb[r], 0.f);
                        short hi, lo; bsplit(v, hi, lo);
                        hh[r] = hi; hl[r] = lo;
                    }
                }
                const int ad = bnBase + ln * 32 + nn * 16 + l4 * 4;
                *(s16x4*)(bnH + ad) = hh;
                *(s16x4*)(bnL + ad) = hl;
            }
            s16x8 b3h = *(const s16x8*)(bnH + bnBase + ln * 32 + klo);
            s16x8 b3l = *(const s16x8*)(bnL + bnBase + ln * 32 + klo);
            #pragma unroll
            for (int n3 = 0; n3 < 5; ++n3) {
                const int off = ((n3 * 4 + ks3) * 64 + l) * 8;
                s16x8 a3h = *(const s16x8*)(sw3h + off);
                s16x8 a3l = *(const s16x8*)(sw3l + off);
                acc3[n3] = __builtin_amdgcn_mfma_f32_16x16x32_bf16(a3h, b3h, acc3[n3], 0, 0, 0);
                acc3[n3] = __builtin_amdgcn_mfma_f32_16x16x32_bf16(a3h, b3l, acc3[n3], 0, 0, 0);
                acc3[n3] = __builtin_amdgcn_mfma_f32_16x16x32_bf16(a3l, b3h, acc3[n3], 0, 0, 0);
            }
        }

        // bias + relu + pool (16 ln-lanes shfl, cross-wave via global atomics)
        float* pb = pooledG + (size_t)b * 80;
        #pragma unroll
        for (int n3 = 0; n3 < 5; ++n3) {
            const int o0 = 16 * n3 + 4 * l4;
            f32x4 bb = *(const f32x4*)(sb3 + o0);
            #pragma unroll
            for (int r = 0; r < 4; ++r) {
                float v = fmaxf(acc3[n3][r] + bb[r], 0.f);
                v += __shfl_xor(v, 1);
                v += __shfl_xor(v, 2);
                v += __shfl_xor(v, 4);
                v += __shfl_xor(v, 8);
                if (ln == 0) atomicAdd(pb + o0 + r, v);
            }
        }
    }
}

// Tail: 512 blocks x 256 thr; each block does 4 batches (weights stay hot in L1).
__global__ __launch_bounds__(256, 4)
void ds_tail(const float* __restrict__ pooledG, const float* __restrict__ stat,
             const float* __restrict__ rw1, const float* __restrict__ rb1,
             const float* __restrict__ rw2, const float* __restrict__ rb2,
             const float* __restrict__ rw3, const float* __restrict__ rb3,
             const float* __restrict__ qw1, const float* __restrict__ qb1,
             const float* __restrict__ qw2, const float* __restrict__ qb2,
             const float* __restrict__ qw3, const float* __restrict__ qb3,
             float* __restrict__ out) {
    const int tid = threadIdx.x;
    __shared__ __align__(16) float r1s[64], r2s[64], xcat[48], q1s[200], q2s[104];
    __shared__ float logits[3];

    for (int g = 0; g < 4; ++g) {
        const int b = blockIdx.x * 4 + g;
        const float* pooled = pooledG + (size_t)b * 80;

        if (tid < 60) {
            float a = rb1[tid];
            for (int k = 0; k < 80; k += 4) {
                f32x4 pv = *(const f32x4*)(pooled + k);
                f32x4 wv = *(const f32x4*)(rw1 + tid * 80 + k);
                a += pv.x * wv.x + pv.y * wv.y + pv.z * wv.z + pv.w * wv.w;
            }
            r1s[tid] = fmaxf(a, 0.0f);
        }
        __syncthreads();
        if (tid < 60) {
            float a = rb2[tid];
            for (int k = 0; k < 60; k += 4) {
                f32x4 pv = *(const f32x4*)(r1s + k);
                f32x4 wv = *(const f32x4*)(rw2 + tid * 60 + k);
                a += pv.x * wv.x + pv.y * wv.y + pv.z * wv.z + pv.w * wv.w;
            }
            r2s[tid] = fmaxf(a, 0.0f);
        }
        __syncthreads();
        if (tid < 40) {
            float a = rb3[tid];
            for (int k = 0; k < 60; k += 4) {
                f32x4 pv = *(const f32x4*)(r2s + k);
                f32x4 wv = *(const f32x4*)(rw3 + tid * 60 + k);
                a += pv.x * wv.x + pv.y * wv.y + pv.z * wv.z + pv.w * wv.w;
            }
            xcat[tid] = a;
        }
        if (tid >= 40 && tid < 43) xcat[tid] = stat[(size_t)b * 3 + (tid - 40)];
        __syncthreads();
        if (tid < 200) {
            float a = qb1[tid];
            const float* wv = qw1 + tid * 43;
            for (int k = 0; k < 43; ++k) a += xcat[k] * wv[k];
            q1s[tid] = fmaxf(a, 0.0f);
        }
        __syncthreads();
        if (tid < 100) {
            float a = qb2[tid];
            for (int k = 0; k < 200; k += 4) {
                f32x4 pv = *(const f32x4*)(q1s + k);
                f32x4 wv = *(const f32x4*)(qw2 + tid * 200 + k);
                a += pv.x * wv.x + pv.y * wv.y + pv.z * wv.z + pv.w * wv.w;
            }
            q2s[tid] = fmaxf(a, 0.0f);
        }
        __syncthreads();
        if (tid < 96) {
            int o = tid >> 5, l2 = tid & 31;
            float a = 0.0f;
            for (int k = l2; k < 100; k += 32) a += q2s[k] * qw3[o * 100 + k];
            #pragma unroll
            for (int d = 16; d > 0; d >>= 1) a += __shfl_down(a, d, 32);
            if (l2 == 0) logits[o] = a + qb3[o];
        }
        __syncthreads();
        if (tid < 3) {
            float l0 = logits[0], l1 = logits[1], l2v = logits[2];
            float m  = fmaxf(l0, fmaxf(l1, l2v));
            float e0 = __expf(l0 - m), e1 = __expf(l1 - m), e2 = __expf(l2v - m);
            float inv = 1.0f / (e0 + e1 + e2);
            float mine = (tid == 0) ? e0 : ((tid == 1) ? e1 : e2);
            out[(size_t)b * 3 + tid] = mine * inv;
        }
        __syncthreads();
    }
}

extern "C" void kernel_launch(void* const* d_in, const int* in_sizes, int n_in,
                              void* d_out, int out_size, void* d_ws, size_t ws_size,
                              hipStream_t stream) {
    const float* dyn  = (const float*)d_in[0];
    const float* stat = (const float*)d_in[1];
    const float* pw1  = (const float*)d_in[2];
    const float* pb1  = (const float*)d_in[3];
    const float* pw2  = (const float*)d_in[4];
    const float* pb2  = (const float*)d_in[5];
    const float* pw3  = (const float*)d_in[6];
    const float* pb3  = (const float*)d_in[7];
    const float* rw1  = (const float*)d_in[8];
    const float* rb1  = (const float*)d_in[9];
    const float* rw2  = (const float*)d_in[10];
    const float* rb2  = (const float*)d_in[11];
    const float* rw3  = (const float*)d_in[12];
    const float* rb3  = (const float*)d_in[13];
    const float* qw1  = (const float*)d_in[14];
    const float* qb1  = (const float*)d_in[15];
    const float* qw2  = (const float*)d_in[16];
    const float* qb2  = (const float*)d_in[17];
    const float* qw3  = (const float*)d_in[18];
    const float* qb3  = (const float*)d_in[19];
    float* out = (float*)d_out;

    float* wsF = (float*)d_ws;
    short* wsS = (short*)(wsF + WSHORT_OFF);
    float* pooledG = wsF + POOLED_OFF;
    const int B = in_sizes[0] / 384;   // 2048

    ds_prep<<<dim3(258), dim3(256), 0, stream>>>(pw1, pb1, pw2, pb2, pw3, pb3, wsF, wsS);
    ds_phi<<<dim3(B / 8), dim3(512), 0, stream>>>(dyn, wsF, wsS, pooledG);
    ds_tail<<<dim3(B / 4), dim3(256), 0, stream>>>(pooledG, stat,
        rw1, rb1, rw2, rb2, rw3, rb3,
        qw1, qb1, qw2, qb2, qw3, qb3, out);
}

// Round 5
// 362.008 us; speedup vs baseline: 1.2298x; 1.2298x over previous
//
#include <hip/hip_runtime.h>
#include <math.h>

typedef short s16x8 __attribute__((ext_vector_type(8)));
typedef short s16x4 __attribute__((ext_vector_type(4)));
typedef float f32x4 __attribute__((ext_vector_type(4)));

// ws float-offsets (pooled region kept at 0 for tail)
#define POOLED_OFF 0           // 2048*80 floats
#define W1PK_OFF   163840      // 128 x {w1c0,w1c1,w1c2,b1}
#define B2PK_OFF   164352      // 112 floats (zero-padded)
#define B3PK_OFF   164464      // 80 floats
#define WSHORT_OFF 164560      // short region (16B aligned)
// short-offsets inside short region (frag-ordered, per (n,ks): 512 shorts)
#define W2H_S 0                // 7*4*512 = 14336
#define W2L_S 14336
#define W3H_S 28672            // 5*4*512 = 10240
#define W3L_S 38912

__device__ __forceinline__ void bsplit(float x, short& hi, short& lo) {
    unsigned u  = __float_as_uint(x);
    unsigned uh = u & 0xFFFF0000u;
    hi = (short)(uh >> 16);
    float r = x - __uint_as_float(uh);
    lo = (short)(__float_as_uint(r) >> 16);
}

// Prep: pack w1/b1 rows, pad biases, frag-ordered split weights.
// Frag (n,ks): lane=ln+16*l4 holds w[16n+ln][ks*32+l4*8+j], j=0..7.
__global__ void ds_prep(const float* __restrict__ pw1, const float* __restrict__ pb1,
                        const float* __restrict__ pw2, const float* __restrict__ pb2,
                        const float* __restrict__ pw3, const float* __restrict__ pb3,
                        float* __restrict__ wsF, short* __restrict__ wsS) {
    int t = blockIdx.x * 256 + threadIdx.x;
    if (t < 128) {
        f32x4 v = 0.f;
        if (t < 120) { v.x = pw1[t*3]; v.y = pw1[t*3+1]; v.z = pw1[t*3+2]; v.w = pb1[t]; }
        *(f32x4*)(wsF + W1PK_OFF + t * 4) = v; return;
    }
    t -= 128;
    if (t < 112) { wsF[B2PK_OFF + t] = (t < 100) ? pb2[t] : 0.f; return; }
    t -= 112;
    if (t < 80)  { wsF[B3PK_OFF + t] = pb3[t]; return; }
    t -= 80;
    if (t < 14336) {
        int j = t & 7, lane = (t >> 3) & 63, c = t >> 9;
        int ks = c & 3, n = c >> 2;
        int ln = lane & 15, l4 = lane >> 4;
        int row = 16 * n + ln, col = ks * 32 + l4 * 8 + j;
        float v = (row < 100 && col < 120) ? pw2[row * 120 + col] : 0.f;
        short hi, lo; bsplit(v, hi, lo);
        wsS[W2H_S + t] = hi; wsS[W2L_S + t] = lo; return;
    }
    t -= 14336;
    if (t < 10240) {
        int j = t & 7, lane = (t >> 3) & 63, c = t >> 9;
        int ks = c & 3, n = c >> 2;
        int ln = lane & 15, l4 = lane >> 4;
        int row = 16 * n + ln, col = ks * 32 + l4 * 8 + j;
        float v = (col < 100) ? pw3[row * 100 + col] : 0.f;
        short hi, lo; bsplit(v, hi, lo);
        wsS[W3H_S + t] = hi; wsS[W3L_S + t] = lo; return;
    }
}

#define MFMA_B16(A, B, C) __builtin_amdgcn_mfma_f32_16x16x32_bf16((A), (B), (C), 0, 0, 0)

// one K-slice of an L2 o-tile: A-frags straight from global (L2-resident)
#define L2KS(N2, KS, BH, BL) do {                                               \
    const s16x8 ah = *(const s16x8*)(w2h + (((N2) * 4 + (KS)) * 64 + l) * 8);   \
    const s16x8 al = *(const s16x8*)(w2l + (((N2) * 4 + (KS)) * 64 + l) * 8);   \
    a2h = MFMA_B16(ah, BH, a2h);                                                \
    a2x = MFMA_B16(ah, BL, a2x);                                                \
    a2x = MFMA_B16(al, BH, a2x);                                                \
} while (0)

// full L2 o-tile N2 -> bias+relu+split into HH/HL (s16x4)
#define L2TILE(N2, HH, HL) do {                                                 \
    f32x4 a2h = 0.f, a2x = 0.f;                                                 \
    L2KS(N2, 0, bh1_0, bl1_0);                                                  \
    L2KS(N2, 1, bh1_1, bl1_1);                                                  \
    L2KS(N2, 2, bh1_2, bl1_2);                                                  \
    L2KS(N2, 3, bh1_3, bl1_3);                                                  \
    const int o0 = 16 * (N2) + 4 * l4;                                          \
    f32x4 bb = *(const f32x4*)(sb2 + o0);                                       \
    _Pragma("unroll")                                                           \
    for (int r = 0; r < 4; ++r) {                                               \
        float v = fmaxf(a2h[r] + a2x[r] + bb[r], 0.f);                          \
        short hi, lo; bsplit(v, hi, lo);                                        \
        HH[r] = hi; HL[r] = lo;                                                 \
    }                                                                           \
} while (0)

#define L3KS(N3, KS3, ACC) do {                                                 \
    const s16x8 a3h = *(const s16x8*)(w3h + (((N3) * 4 + (KS3)) * 64 + l) * 8); \
    const s16x8 a3l = *(const s16x8*)(w3l + (((N3) * 4 + (KS3)) * 64 + l) * 8); \
    ACC = MFMA_B16(a3h, b3h, ACC);                                              \
    ACC = MFMA_B16(a3h, b3l, ACC);                                              \
    ACC = MFMA_B16(a3l, b3h, ACC);                                              \
} while (0)

// one h2 k-slice: two L2 o-tiles -> per-wave LDS bounce -> 5 L3 tiles fed
#define KS3_STEP(KS3, N2A, N2B) do {                                            \
    s16x4 hh0 = 0, hl0 = 0, hh1 = 0, hl1 = 0;                                   \
    L2TILE(N2A, hh0, hl0);                                                      \
    if ((N2B) < 7) { L2TILE(N2B, hh1, hl1); }                                   \
    *(s16x4*)(bnH + bnBase + ln * 32 + l4 * 4)      = hh0;                      \
    *(s16x4*)(bnL + bnBase + ln * 32 + l4 * 4)      = hl0;                      \
    *(s16x4*)(bnH + bnBase + ln * 32 + 16 + l4 * 4) = hh1;                      \
    *(s16x4*)(bnL + bnBase + ln * 32 + 16 + l4 * 4) = hl1;                      \
    const s16x8 b3h = *(const s16x8*)(bnH + bnBase + ln * 32 + klo);            \
    const s16x8 b3l = *(const s16x8*)(bnL + bnBase + ln * 32 + klo);            \
    L3KS(0, KS3, acc3_0);                                                       \
    L3KS(1, KS3, acc3_1);                                                       \
    L3KS(2, KS3, acc3_2);                                                       \
    L3KS(3, KS3, acc3_3);                                                       \
    L3KS(4, KS3, acc3_4);                                                       \
} while (0)

#define POOLN(N3, ACC) do {                                                     \
    const int o0 = 16 * (N3) + 4 * l4;                                          \
    f32x4 bb = *(const f32x4*)(sb3 + o0);                                       \
    _Pragma("unroll")                                                           \
    for (int r = 0; r < 4; ++r) {                                               \
        float v = fmaxf(ACC[r] + bb[r], 0.f);                                   \
        v += __shfl_xor(v, 1);                                                  \
        v += __shfl_xor(v, 2);                                                  \
        v += __shfl_xor(v, 4);                                                  \
        v += __shfl_xor(v, 8);                                                  \
        if (ln == 0) pbuf[o0 + r] = v;                                          \
    }                                                                           \
} while (0)

// Phi: 512 blocks x 512 thr; 4 batches/block; wave w owns el-tile w.
// No LDS weight staging; A-frags from global (frag-ordered => coalesced, L2-hot).
__global__ __launch_bounds__(512, 2)
void ds_phi(const float* __restrict__ dyn, const float* __restrict__ wsF,
            const short* __restrict__ wsS, float* __restrict__ pooledG) {
    const int tid = threadIdx.x;
    const int w = tid >> 6, l = tid & 63, ln = l & 15, l4 = l >> 4;
    const int klo = l4 * 8;

    __shared__ float sw1[512], sb2[112], sb3[80];
    __shared__ short bnH[4096], bnL[4096];     // per-wave 512-short bounce
    __shared__ float poolbuf[8 * 80];

    if (tid < 128) *(f32x4*)(sw1 + tid * 4) = *(const f32x4*)(wsF + W1PK_OFF + tid * 4);
    if (tid < 112) sb2[tid] = wsF[B2PK_OFF + tid];
    if (tid < 80)  sb3[tid] = wsF[B3PK_OFF + tid];
    __syncthreads();

    const short* w2h = wsS + W2H_S;
    const short* w2l = wsS + W2L_S;
    const short* w3h = wsS + W3H_S;
    const short* w3l = wsS + W3L_S;
    const int el = 16 * w + ln;
    const int bnBase = w << 9;
    float* pbuf = poolbuf + w * 80;

    #pragma unroll 1
    for (int g = 0; g < 4; ++g) {
        const int b = blockIdx.x * 4 + g;
        const float* xp = dyn + (size_t)b * 384 + el * 3;
        const float x0 = xp[0], x1 = xp[1], x2 = xp[2];

        // h1 B-frags born in registers (k>=120 rows zero via sw1 padding)
        s16x8 bh1_0, bl1_0, bh1_1, bl1_1, bh1_2, bl1_2, bh1_3, bl1_3;
        #define H1GEN(KS, BH, BL) do {                                          \
            _Pragma("unroll")                                                   \
            for (int j = 0; j < 8; ++j) {                                       \
                const int k = (KS) * 32 + klo + j;                              \
                f32x4 c = *(const f32x4*)(sw1 + 4 * k);                         \
                float v = fmaf(x0, c.x, fmaf(x1, c.y, fmaf(x2, c.z, c.w)));     \
                v = fmaxf(v, 0.f);                                              \
                short hi, lo; bsplit(v, hi, lo);                                \
                BH[j] = hi; BL[j] = lo;                                         \
            }                                                                   \
        } while (0)
        H1GEN(0, bh1_0, bl1_0);
        H1GEN(1, bh1_1, bl1_1);
        H1GEN(2, bh1_2, bl1_2);
        H1GEN(3, bh1_3, bl1_3);
        #undef H1GEN

        f32x4 acc3_0 = 0.f, acc3_1 = 0.f, acc3_2 = 0.f, acc3_3 = 0.f, acc3_4 = 0.f;

        KS3_STEP(0, 0, 1);
        KS3_STEP(1, 2, 3);
        KS3_STEP(2, 4, 5);
        KS3_STEP(3, 6, 7);   // n2=7 stays zero

        POOLN(0, acc3_0);
        POOLN(1, acc3_1);
        POOLN(2, acc3_2);
        POOLN(3, acc3_3);
        POOLN(4, acc3_4);
        __syncthreads();
        if (tid < 80) {
            float s = 0.f;
            #pragma unroll
            for (int ww = 0; ww < 8; ++ww) s += poolbuf[ww * 80 + tid];
            pooledG[(size_t)b * 80 + tid] = s;
        }
        __syncthreads();
    }
}

// Tail: 512 blocks x 256 thr; each block does 4 batches.
__global__ __launch_bounds__(256, 4)
void ds_tail(const float* __restrict__ pooledG, const float* __restrict__ stat,
             const float* __restrict__ rw1, const float* __restrict__ rb1,
             const float* __restrict__ rw2, const float* __restrict__ rb2,
             const float* __restrict__ rw3, const float* __restrict__ rb3,
             const float* __restrict__ qw1, const float* __restrict__ qb1,
             const float* __restrict__ qw2, const float* __restrict__ qb2,
             const float* __restrict__ qw3, const float* __restrict__ qb3,
             float* __restrict__ out) {
    const int tid = threadIdx.x;
    __shared__ __align__(16) float r1s[64], r2s[64], xcat[48], q1s[200], q2s[104];
    __shared__ float logits[3];

    #pragma unroll 1
    for (int g = 0; g < 4; ++g) {
        const int b = blockIdx.x * 4 + g;
        const float* pooled = pooledG + (size_t)b * 80;

        if (tid < 60) {
            float a = rb1[tid];
            for (int k = 0; k < 80; k += 4) {
                f32x4 pv = *(const f32x4*)(pooled + k);
                f32x4 wv = *(const f32x4*)(rw1 + tid * 80 + k);
                a += pv.x * wv.x + pv.y * wv.y + pv.z * wv.z + pv.w * wv.w;
            }
            r1s[tid] = fmaxf(a, 0.0f);
        }
        __syncthreads();
        if (tid < 60) {
            float a = rb2[tid];
            for (int k = 0; k < 60; k += 4) {
                f32x4 pv = *(const f32x4*)(r1s + k);
                f32x4 wv = *(const f32x4*)(rw2 + tid * 60 + k);
                a += pv.x * wv.x + pv.y * wv.y + pv.z * wv.z + pv.w * wv.w;
            }
            r2s[tid] = fmaxf(a, 0.0f);
        }
        __syncthreads();
        if (tid < 40) {
            float a = rb3[tid];
            for (int k = 0; k < 60; k += 4) {
                f32x4 pv = *(const f32x4*)(r2s + k);
                f32x4 wv = *(const f32x4*)(rw3 + tid * 60 + k);
                a += pv.x * wv.x + pv.y * wv.y + pv.z * wv.z + pv.w * wv.w;
            }
            xcat[tid] = a;
        }
        if (tid >= 40 && tid < 43) xcat[tid] = stat[(size_t)b * 3 + (tid - 40)];
        __syncthreads();
        if (tid < 200) {
            float a = qb1[tid];
            const float* wv = qw1 + tid * 43;
            for (int k = 0; k < 43; ++k) a += xcat[k] * wv[k];
            q1s[tid] = fmaxf(a, 0.0f);
        }
        __syncthreads();
        if (tid < 100) {
            float a = qb2[tid];
            for (int k = 0; k < 200; k += 4) {
                f32x4 pv = *(const f32x4*)(q1s + k);
                f32x4 wv = *(const f32x4*)(qw2 + tid * 200 + k);
                a += pv.x * wv.x + pv.y * wv.y + pv.z * wv.z + pv.w * wv.w;
            }
            q2s[tid] = fmaxf(a, 0.0f);
        }
        __syncthreads();
        if (tid < 96) {
            int o = tid >> 5, l2 = tid & 31;
            float a = 0.0f;
            for (int k = l2; k < 100; k += 32) a += q2s[k] * qw3[o * 100 + k];
            #pragma unroll
            for (int d = 16; d > 0; d >>= 1) a += __shfl_down(a, d, 32);
            if (l2 == 0) logits[o] = a + qb3[o];
        }
        __syncthreads();
        if (tid < 3) {
            float l0 = logits[0], l1 = logits[1], l2v = logits[2];
            float m  = fmaxf(l0, fmaxf(l1, l2v));
            float e0 = __expf(l0 - m), e1 = __expf(l1 - m), e2 = __expf(l2v - m);
            float inv = 1.0f / (e0 + e1 + e2);
            float mine = (tid == 0) ? e0 : ((tid == 1) ? e1 : e2);
            out[(size_t)b * 3 + tid] = mine * inv;
        }
        __syncthreads();
    }
}

extern "C" void kernel_launch(void* const* d_in, const int* in_sizes, int n_in,
                              void* d_out, int out_size, void* d_ws, size_t ws_size,
                              hipStream_t stream) {
    const float* dyn  = (const float*)d_in[0];
    const float* stat = (const float*)d_in[1];
    const float* pw1  = (const float*)d_in[2];
    const float* pb1  = (const float*)d_in[3];
    const float* pw2  = (const float*)d_in[4];
    const float* pb2  = (const float*)d_in[5];
    const float* pw3  = (const float*)d_in[6];
    const float* pb3  = (const float*)d_in[7];
    const float* rw1  = (const float*)d_in[8];
    const float* rb1  = (const float*)d_in[9];
    const float* rw2  = (const float*)d_in[10];
    const float* rb2  = (const float*)d_in[11];
    const float* rw3  = (const float*)d_in[12];
    const float* rb3  = (const float*)d_in[13];
    const float* qw1  = (const float*)d_in[14];
    const float* qb1  = (const float*)d_in[15];
    const float* qw2  = (const float*)d_in[16];
    const float* qb2  = (const float*)d_in[17];
    const float* qw3  = (const float*)d_in[18];
    const float* qb3  = (const float*)d_in[19];
    float* out = (float*)d_out;

    float* wsF = (float*)d_ws;
    short* wsS = (short*)(wsF + WSHORT_OFF);
    float* pooledG = wsF + POOLED_OFF;
    const int B = in_sizes[0] / 384;   // 2048

    ds_prep<<<dim3(98), dim3(256), 0, stream>>>(pw1, pb1, pw2, pb2, pw3, pb3, wsF, wsS);
    ds_phi<<<dim3(B / 4), dim3(512), 0, stream>>>(dyn, wsF, wsS, pooledG);
    ds_tail<<<dim3(B / 4), dim3(256), 0, stream>>>(pooledG, stat,
        rw1, rb1, rw2, rb2, rw3, rb3,
        qw1, qb1, qw2, qb2, qw3, qb3, out);
}